// Round 7
// baseline (6204.535 us; speedup 1.0000x reference)
//
#include <hip/hip_runtime.h>
#include <math.h>
#include <stdint.h>
#include <stddef.h>

// Problem dims (hard-coded per reference)
#define B_ 512
#define H_ 512
#define E_ 512
#define V_ 2048
#define IN_ 1024
#define LSTEPS 32
#define LP1 33

// JAX threefry mode: 1 = partitionable (JAX >= 0.4.36 default), 0 = original
#define TF_PARTITIONABLE 1

#define NBLOCKS 256
#define NGROUPS 8
#define GSIZE (NBLOCKS / NGROUPS)     // 32 blocks per group
#define SPIN_LIMIT 500000

// barrier word layout (uint32 indices into bar[]):
//   group g arrival counter : g*32          (128-B separated lines)
//   leader counter          : 256
//   group g release epoch   : 288 + g*32
#define BAR_WORDS 544

typedef unsigned short u16;
typedef __attribute__((ext_vector_type(8))) short bhalf8;   // 8 bf16 = 4 VGPR
typedef __attribute__((ext_vector_type(4))) float f32x4;

__device__ __forceinline__ void tf2x32(uint32_t k0, uint32_t k1,
                                       uint32_t x0, uint32_t x1,
                                       uint32_t& o0, uint32_t& o1) {
  uint32_t ks2 = k0 ^ k1 ^ 0x1BD11BDAu;
  x0 += k0; x1 += k1;
#define TFR(R) { x0 += x1; x1 = (x1 << (R)) | (x1 >> (32 - (R))); x1 ^= x0; }
  TFR(13) TFR(15) TFR(26) TFR(6)
  x0 += k1; x1 += ks2 + 1u;
  TFR(17) TFR(29) TFR(16) TFR(24)
  x0 += ks2; x1 += k0 + 2u;
  TFR(13) TFR(15) TFR(26) TFR(6)
  x0 += k0; x1 += k1 + 3u;
  TFR(17) TFR(29) TFR(16) TFR(24)
  x0 += k1; x1 += ks2 + 4u;
  TFR(13) TFR(15) TFR(26) TFR(6)
  x0 += ks2; x1 += k0 + 5u;
#undef TFR
  o0 = x0; o1 = x1;
}

__global__ void init_keys_kernel(uint32_t* __restrict__ sk, uint32_t* __restrict__ bar) {
  for (int i = 0; i < BAR_WORDS; i++) bar[i] = 0u;   // reset each graph replay
  uint32_t k0 = 0u, k1 = 1u;
  for (int t = 0; t < LSTEPS; t++) {
    uint32_t a0, a1, b0, b1;
#if TF_PARTITIONABLE
    tf2x32(k0, k1, 0u, 0u, a0, a1);
    tf2x32(k0, k1, 0u, 1u, b0, b1);
    sk[2 * t] = b0; sk[2 * t + 1] = b1;
    k0 = a0; k1 = a1;
#else
    tf2x32(k0, k1, 0u, 2u, a0, a1);
    tf2x32(k0, k1, 1u, 3u, b0, b1);
    sk[2 * t] = a1; sk[2 * t + 1] = b1;
    k0 = a0; k1 = b0;
#endif
  }
}

// ---- bf16x3 split (RNE at each stage; hi+mid+lo represents fp32 to 2^-27)
__device__ __forceinline__ void split3(float v, u16& h, u16& m, u16& l) {
  uint32_t u = __float_as_uint(v);
  uint32_t r = (u + 0x7FFFu + ((u >> 16) & 1u)) >> 16;
  h = (u16)r;
  float res = v - __uint_as_float(r << 16);
  uint32_t u2 = __float_as_uint(res);
  uint32_t r2 = (u2 + 0x7FFFu + ((u2 >> 16) & 1u)) >> 16;
  m = (u16)r2;
  float res2 = res - __uint_as_float(r2 << 16);
  uint32_t u3 = __float_as_uint(res2);
  uint32_t r3 = (u3 + 0x7FFFu + ((u3 >> 16) & 1u)) >> 16;
  l = (u16)r3;
}

__global__ __launch_bounds__(256) void init_state_planes_kernel(
    const float* __restrict__ sos, float* __restrict__ c,
    u16* __restrict__ eh, u16* __restrict__ em, u16* __restrict__ el) {
  int idx = blockIdx.x * 256 + threadIdx.x;
  if (idx < B_ * H_) {
    c[idx] = 0.0f;
    u16 a, b2, d;
    split3(sos[idx & (E_ - 1)], a, b2, d);
    eh[idx] = a; em[idx] = b2; el[idx] = d;
  }
}

__global__ __launch_bounds__(256) void eos_fill_kernel(
    float* __restrict__ o_seq, float* __restrict__ o_probs,
    float* __restrict__ o_logp, float* __restrict__ o_ent) {
  int b = blockIdx.x, tid = threadIdx.x;
  float* pr = o_probs + ((size_t)b * LP1 + LSTEPS) * V_;
  for (int v = tid; v < V_; v += 256) pr[v] = 1.0f;
  if (tid == 0) {
    o_seq[b * LP1 + LSTEPS] = 0.0f;
    o_logp[b * LP1 + LSTEPS] = 0.0f;
    o_ent[b * LP1 + LSTEPS] = 0.0f;
  }
}

// elementwise fp32 -> 3 bf16 planes (same layout)
__global__ __launch_bounds__(256) void split_kernel(
    const float* __restrict__ src,
    u16* __restrict__ dh, u16* __restrict__ dm, u16* __restrict__ dl, int n) {
  int i = blockIdx.x * 256 + threadIdx.x;
  if (i < n) {
    u16 a, b2, d;
    split3(src[i], a, b2, d);
    dh[i] = a; dm[i] = b2; dl[i] = d;
  }
}

// src [srcK][srcN] fp32 -> dst planes [srcN][dstK] bf16 at column offset kOff
__global__ __launch_bounds__(256) void transpose_split_kernel(
    const float* __restrict__ src, int srcN,
    u16* __restrict__ dh, u16* __restrict__ dm, u16* __restrict__ dl,
    int dstK, int kOff) {
  __shared__ float t[32][33];
  int tx = threadIdx.x & 31, ty = threadIdx.x >> 5;   // 32 x 8
  int kt = blockIdx.x * 32, nt = blockIdx.y * 32;
#pragma unroll
  for (int j = 0; j < 4; j++)
    t[ty + j * 8][tx] = src[(size_t)(kt + ty + j * 8) * srcN + nt + tx];
  __syncthreads();
#pragma unroll
  for (int j = 0; j < 4; j++) {
    int n = nt + ty + j * 8;
    int k = kt + tx;
    u16 a, b2, d;
    split3(t[tx][ty + j * 8], a, b2, d);
    size_t o = (size_t)n * dstK + kOff + k;
    dh[o] = a; dm[o] = b2; dl[o] = d;
  }
}

// ---- async global->LDS staging helper (16B per lane, wave-uniform LDS base)
typedef __attribute__((address_space(1))) const void GASV;
typedef __attribute__((address_space(3))) void LASV;
__device__ __forceinline__ void gld16(const void* g, void* l) {
  __builtin_amdgcn_global_load_lds((GASV*)g, (LASV*)l, 16, 0, 0);
}

// ---- hierarchical grid barrier v2.
// Level 1: per-group (bid&7) arrival counter on its own 128-B line -> RMWs
// stay (mostly) XCD-local and the 8 groups proceed in parallel.
// Level 2: 32nd arriver of each group RMWs the leader counter (8 cross-XCD
// RMWs); 8th leader RELEASE-stores each group's epoch flag; everyone else
// ACQUIRE-spins on its group flag (shared read-only line, no bouncing).
// Monotonic epochs; agent scope; sticky-dead valve (never hangs).
__device__ __forceinline__ void grid_barrier(uint32_t* bar, uint32_t* gen, int* dead) {
  __syncthreads();
  if (threadIdx.x == 0) {
    uint32_t e = *gen + 1u;
    *gen = e;
    int g = blockIdx.x & (NGROUPS - 1);
    uint32_t* agrp = bar + g * 32;
    uint32_t* lead = bar + 256;
    uint32_t* rel  = bar + 288 + g * 32;
    uint32_t a = __hip_atomic_fetch_add(agrp, 1u, __ATOMIC_ACQ_REL,
                                        __HIP_MEMORY_SCOPE_AGENT) + 1u;
    if (!*dead) {
      if (a == e * (uint32_t)GSIZE) {          // group leader for this epoch
        uint32_t l = __hip_atomic_fetch_add(lead, 1u, __ATOMIC_ACQ_REL,
                                            __HIP_MEMORY_SCOPE_AGENT) + 1u;
        if (l == e * (uint32_t)NGROUPS) {      // last leader: release everyone
#pragma unroll
          for (int i = 0; i < NGROUPS; i++)
            __hip_atomic_store(bar + 288 + i * 32, e, __ATOMIC_RELEASE,
                               __HIP_MEMORY_SCOPE_AGENT);
        } else {
          int spins = 0;
          while (__hip_atomic_load(rel, __ATOMIC_ACQUIRE,
                                   __HIP_MEMORY_SCOPE_AGENT) < e) {
            __builtin_amdgcn_s_sleep(1);
            if (++spins > SPIN_LIMIT) { *dead = 1; break; }
          }
        }
      } else {
        int spins = 0;
        while (__hip_atomic_load(rel, __ATOMIC_ACQUIRE,
                                 __HIP_MEMORY_SCOPE_AGENT) < e) {
          __builtin_amdgcn_s_sleep(1);
          if (++spins > SPIN_LIMIT) { *dead = 1; break; }
        }
      }
    }
  }
  __syncthreads();
}

// ============================================================================
// bf16x3 MFMA GEMM phase (device function). C = A @ B(pre-transposed, [N][K]).
// A planes: [M][K] bf16 (k-contig). k < kHalf -> A0*, else A1* (k-kHalf).
// Requires grid == 8 * (N/64); M fixed 512 (8 m-tiles of 64).
// 256 threads, 4 waves, wave-tile 32x32, acc 2x2 frags of 16x16x32_bf16.
// LDS: 2 bufs x 6 planes x [64 rows][32 k] bf16 = 48 KB.
// Slot swizzle (verified R2/R3): stored_byte(r,s) = r*64 + ((s ^ ((r>>1)&3)) << 4).
// ============================================================================
__device__ __forceinline__ void gemm_phase(
    const u16* A0h, const u16* A0m, const u16* A0l,
    const u16* A1h, const u16* A1m, const u16* A1l,
    int strideA, int kHalf,
    const u16* Bh, const u16* Bm, const u16* Bl,
    int strideB, int N, int K,
    float* C, char* ldsbase) {
  int tid = threadIdx.x;
  int w = tid >> 6, l = tid & 63;
  int bid = blockIdx.x;
  int gridN = N >> 6;
  int xcd = bid & 7, mIdx = (bid >> 3) & 7, cIdx = bid >> 6;
  int nIdx = xcd * (gridN >> 3) + cIdx;
  int m0 = mIdx * 64, n0 = nIdx * 64;

  int srow = l >> 2;
  int slog = (l & 3) ^ ((l >> 3) & 3);
  size_t aRow = (size_t)(m0 + w * 16 + srow) * strideA + slog * 8;
  size_t bRow = (size_t)(n0 + w * 16 + srow) * strideB + slog * 8;

  int lrow = l & 15, lk8 = l >> 4;
  int xorv = (lrow >> 1) & 3;
  int wr = (w >> 1) * 32, wc = (w & 1) * 32;
  int fOffA = (wr + lrow) * 64 + ((lk8 ^ xorv) << 4);
  int fOffB = (wc + lrow) * 64 + ((lk8 ^ xorv) << 4);

  f32x4 acc[2][2] = {};
  int nch = K >> 5;

#define STAGEP(CH, TB) {                                                \
    int kc = (CH) << 5;                                                 \
    bool hi2 = kc >= kHalf;                                             \
    const u16* Ah2 = hi2 ? A1h : A0h;                                   \
    const u16* Am2 = hi2 ? A1m : A0m;                                   \
    const u16* Al2 = hi2 ? A1l : A0l;                                   \
    size_t ao = aRow + (hi2 ? kc - kHalf : kc);                         \
    size_t bo = bRow + kc;                                              \
    char* Lb = ldsbase + (TB) * 24576 + w * 1024;                       \
    gld16(Ah2 + ao, Lb + 0 * 4096);                                     \
    gld16(Am2 + ao, Lb + 1 * 4096);                                     \
    gld16(Al2 + ao, Lb + 2 * 4096);                                     \
    gld16(Bh + bo, Lb + 3 * 4096);                                      \
    gld16(Bm + bo, Lb + 4 * 4096);                                      \
    gld16(Bl + bo, Lb + 5 * 4096);                                      \
  }

  STAGEP(0, 0)
  for (int ch = 0; ch < nch; ch++) {
    __syncthreads();                 // drains vmcnt -> buf[ch&1] staged
    if (ch + 1 < nch) STAGEP(ch + 1, (ch + 1) & 1)
    const char* base = ldsbase + (ch & 1) * 24576;
    bhalf8 af[3][2], bfr[3][2];
#pragma unroll
    for (int p = 0; p < 3; p++) {
#pragma unroll
      for (int m = 0; m < 2; m++)
        af[p][m] = *(const bhalf8*)(base + p * 4096 + fOffA + m * 1024);
#pragma unroll
      for (int n = 0; n < 2; n++)
        bfr[p][n] = *(const bhalf8*)(base + (3 + p) * 4096 + fOffB + n * 1024);
    }
    const int PA[6] = {2, 0, 1, 1, 0, 0};
    const int PB[6] = {0, 2, 1, 0, 1, 0};
#pragma unroll
    for (int pp = 0; pp < 6; pp++) {
#pragma unroll
      for (int m = 0; m < 2; m++) {
#pragma unroll
        for (int n = 0; n < 2; n++) {
          acc[m][n] = __builtin_amdgcn_mfma_f32_16x16x32_bf16(
              af[PA[pp]][m], bfr[PB[pp]][n], acc[m][n], 0, 0, 0);
        }
      }
    }
  }
#undef STAGEP

  __syncthreads();   // all frag reads of last buf done before phase exit
  // C/D layout: col = lane&15, row = (lane>>4)*4 + reg  [m89-verified]
#pragma unroll
  for (int m = 0; m < 2; m++) {
#pragma unroll
    for (int n = 0; n < 2; n++) {
#pragma unroll
      for (int j = 0; j < 4; j++) {
        int row = m0 + wr + m * 16 + lk8 * 4 + j;
        int col = n0 + wc + n * 16 + lrow;
        C[(size_t)row * N + col] = acc[m][n][j];
      }
    }
  }
}

__device__ __forceinline__ float sigm(float x) { return 1.0f / (1.0f + expf(-x)); }

// Gates [B][2048] fp32 + biases -> LSTM cell -> c fp32 + h planes.
// Requires grid * 256 == B_*H_/4 (= 65536).
__device__ __forceinline__ void cell_phase(
    const float* G, const float* b_ih, const float* b_hh,
    float* c, u16* hh_, u16* hm_, u16* hl_) {
  int idx = blockIdx.x * 256 + threadIdx.x;   // float4 index in [B, H] space
  int b = idx >> 7;
  int h4 = (idx & 127) * 4;
  float4 g4[4];
#pragma unroll
  for (int g = 0; g < 4; g++) {
    size_t off = (size_t)b * 2048 + g * 512 + h4;
    float4 s = *(const float4*)&G[off];
    float4 bi = *(const float4*)&b_ih[g * 512 + h4];
    float4 bh = *(const float4*)&b_hh[g * 512 + h4];
    s.x += bi.x + bh.x; s.y += bi.y + bh.y; s.z += bi.z + bh.z; s.w += bi.w + bh.w;
    g4[g] = s;
  }
  size_t ci = (size_t)b * 512 + h4;
  float4 cold = *(const float4*)&c[ci];
  float4 cn;
  float hv[4];
  {
    const float* ig = (const float*)&g4[0];
    const float* fg = (const float*)&g4[1];
    const float* gg = (const float*)&g4[2];
    const float* og = (const float*)&g4[3];
    float* cc = (float*)&cn;
    const float* co = (const float*)&cold;
#pragma unroll
    for (int k = 0; k < 4; k++) {
      float cv = sigm(fg[k]) * co[k] + sigm(ig[k]) * tanhf(gg[k]);
      cc[k] = cv;
      hv[k] = sigm(og[k]) * tanhf(cv);
    }
  }
  *(float4*)&c[ci] = cn;
  ushort4 vh, vm, vl;
  u16 a, b2, d;
  split3(hv[0], a, b2, d); vh.x = a; vm.x = b2; vl.x = d;
  split3(hv[1], a, b2, d); vh.y = a; vm.y = b2; vl.y = d;
  split3(hv[2], a, b2, d); vh.z = a; vm.z = b2; vl.z = d;
  split3(hv[3], a, b2, d); vh.w = a; vm.w = b2; vl.w = d;
  *(ushort4*)&hh_[ci] = vh;
  *(ushort4*)&hm_[ci] = vm;
  *(ushort4*)&hl_[ci] = vl;
}

// One row of sample: logits Z[b] (+out_b), log_softmax, entropy, probs write,
// threefry gumbel argmax, logp, embedding-plane gather into e.
__device__ __forceinline__ void sample_row(
    const float* Z, const float* out_b, const uint32_t* skv,
    const u16* ebH, const u16* ebM, const u16* ebL,
    u16* eh, u16* em_, u16* el_,
    float* o_seq, float* o_probs, float* o_logp, float* o_ent, int t, int b,
    float* zs, float* rmax, float* rsum, float* rps, float* rav, int* rai) {
  int tid = threadIdx.x;
  int wid = tid >> 6;
  __syncthreads();   // zs/r* reuse across rows/steps
  const float* pr0 = Z + (size_t)b * V_ + tid * 8;
  float4 za = *(const float4*)pr0;
  float4 zb = *(const float4*)(pr0 + 4);
  {
    float4 oa = *(const float4*)(out_b + tid * 8);
    float4 ob = *(const float4*)(out_b + tid * 8 + 4);
    za.x += oa.x; za.y += oa.y; za.z += oa.z; za.w += oa.w;
    zb.x += ob.x; zb.y += ob.y; zb.z += ob.z; zb.w += ob.w;
  }
  float zv[8] = {za.x, za.y, za.z, za.w, zb.x, zb.y, zb.z, zb.w};
  *(float4*)&zs[tid * 8] = za;
  *(float4*)&zs[tid * 8 + 4] = zb;

  float m = zv[0];
#pragma unroll
  for (int i = 1; i < 8; i++) m = fmaxf(m, zv[i]);
  for (int off = 32; off; off >>= 1) m = fmaxf(m, __shfl_xor(m, off));
  if ((tid & 63) == 0) rmax[wid] = m;
  __syncthreads();
  m = fmaxf(fmaxf(rmax[0], rmax[1]), fmaxf(rmax[2], rmax[3]));

  float sh[8];
  float ssum = 0.f;
#pragma unroll
  for (int i = 0; i < 8; i++) { sh[i] = zv[i] - m; ssum += expf(sh[i]); }
  for (int off = 32; off; off >>= 1) ssum += __shfl_xor(ssum, off);
  if ((tid & 63) == 0) rsum[wid] = ssum;
  __syncthreads();
  float S = (rsum[0] + rsum[1]) + (rsum[2] + rsum[3]);
  float ls = logf(S);

  uint32_t sk0 = skv[2 * t], sk1 = skv[2 * t + 1];
  float psum = 0.f;
  float best = -INFINITY;
  int bi = 0;
  float pv[8];
#pragma unroll
  for (int i = 0; i < 8; i++) {
    float s = sh[i] - ls;
    float p = expf(s);
    pv[i] = p;
    psum += p * s;
    int v = tid * 8 + i;
    uint32_t o0, o1, bits;
#if TF_PARTITIONABLE
    uint32_t j = (uint32_t)(b * V_ + v);
    tf2x32(sk0, sk1, 0u, j, o0, o1);
    bits = o0 ^ o1;
#else
    uint32_t j = (uint32_t)(b * V_ + v);
    const uint32_t n2 = (uint32_t)(B_ * V_ / 2);
    if (j < n2) { tf2x32(sk0, sk1, j, j + n2, o0, o1); bits = o0; }
    else       { tf2x32(sk0, sk1, j - n2, j, o0, o1); bits = o1; }
#endif
    float f = __uint_as_float((bits >> 9) | 0x3f800000u) - 1.0f;
    float u = fmaxf(f, 1.17549435e-38f);
    float g = -logf(-logf(u));
    float a = s + g;
    if (a > best) { best = a; bi = v; }
  }
  float* prw = o_probs + ((size_t)b * LP1 + t) * V_ + tid * 8;
  *(float4*)prw = make_float4(pv[0], pv[1], pv[2], pv[3]);
  *(float4*)(prw + 4) = make_float4(pv[4], pv[5], pv[6], pv[7]);

  for (int off = 32; off; off >>= 1) psum += __shfl_xor(psum, off);
  for (int off = 32; off; off >>= 1) {
    float ov = __shfl_xor(best, off);
    int oi = __shfl_xor(bi, off);
    if (ov > best || (ov == best && oi < bi)) { best = ov; bi = oi; }
  }
  if ((tid & 63) == 0) { rps[wid] = psum; rav[wid] = best; rai[wid] = bi; }
  __syncthreads();
  float ent = -((rps[0] + rps[1]) + (rps[2] + rps[3]));
  float bv2 = rav[0]; int sym = rai[0];
#pragma unroll
  for (int w2 = 1; w2 < 4; w2++) {
    if (rav[w2] > bv2 || (rav[w2] == bv2 && rai[w2] < sym)) { bv2 = rav[w2]; sym = rai[w2]; }
  }
  const u16* gh = ebH + (size_t)sym * E_;
  const u16* gm = ebM + (size_t)sym * E_;
  const u16* gl = ebL + (size_t)sym * E_;
  for (int k2 = tid; k2 < E_; k2 += 256) {
    eh[(size_t)b * E_ + k2]  = gh[k2];
    em_[(size_t)b * E_ + k2] = gm[k2];
    el_[(size_t)b * E_ + k2] = gl[k2];
  }
  if (tid == 0) {
    float s_sym = (zs[sym] - m) - ls;
    o_seq[b * LP1 + t] = (float)sym;
    o_logp[b * LP1 + t] = s_sym;
    o_ent[b * LP1 + t] = ent;
  }
}

// ============================================================================
// Persistent kernel: the whole 32-step loop in one PLAIN dispatch.
// grid = 256 blocks x 256 threads. Phases separated by the hierarchical
// grid barrier. Co-residency by construction: LDS 48KB + VGPR<=256
// (launch_bounds(256,2)) -> capacity 2 blocks/CU = 512 slots >= 256 blocks.
// ============================================================================
struct PK {
  u16 *eH, *eM, *eL;
  u16 *hAH, *hAM, *hAL;
  u16 *hBH, *hBM, *hBL;
  const u16 *gwH, *gwM, *gwL;
  const u16 *owH, *owM, *owL;
  const u16 *ebH, *ebM, *ebL;
  const float *b_ih, *b_hh, *out_b;
  float *c, *G;
  const uint32_t* sk;
  uint32_t* bar;
  float *o_seq, *o_probs, *o_logp, *o_ent;
};

__global__ __launch_bounds__(256, 2) void rnn_persistent_kernel(PK p) {
  __shared__ __align__(16) char smem[2 * 24576];   // gemm staging; zs aliased
  __shared__ float rmax[4], rsum[4], rps[4], rav[4];
  __shared__ int rai[4];
  __shared__ uint32_t bgen;
  __shared__ int bdead;
  char* glds = smem;
  float* zs = (float*)smem;                        // sample phase only (8 KB)

  if (threadIdx.x == 0) { bgen = 0u; bdead = 0; }
  __syncthreads();

  u16 *hiH = p.hAH, *hiM = p.hAM, *hiL = p.hAL;
  u16 *hoH = p.hBH, *hoM = p.hBM, *hoL = p.hBL;

  for (int t = 0; t < LSTEPS; t++) {
    // gates = [e|h] @ [w_ih; w_hh]   (K=1024, kHalf=512) -> G
    gemm_phase(p.eH, p.eM, p.eL, hiH, hiM, hiL, E_, E_,
               p.gwH, p.gwM, p.gwL, IN_, 2048, IN_, p.G, glds);
    grid_barrier(p.bar, &bgen, &bdead);

    cell_phase(p.G, p.b_ih, p.b_hh, p.c, hoH, hoM, hoL);
    grid_barrier(p.bar, &bgen, &bdead);

    // logits = h @ out_w   (K=512) -> G (reused as Z)
    gemm_phase(hoH, hoM, hoL, hoH, hoM, hoL, H_, 1 << 30,
               p.owH, p.owM, p.owL, H_, 2048, H_, p.G, glds);
    grid_barrier(p.bar, &bgen, &bdead);

    // sample: 2 rows per block
    sample_row(p.G, p.out_b, p.sk, p.ebH, p.ebM, p.ebL,
               p.eH, p.eM, p.eL, p.o_seq, p.o_probs, p.o_logp, p.o_ent,
               t, blockIdx.x * 2 + 0, zs, rmax, rsum, rps, rav, rai);
    sample_row(p.G, p.out_b, p.sk, p.ebH, p.ebM, p.ebL,
               p.eH, p.eM, p.eL, p.o_seq, p.o_probs, p.o_logp, p.o_ent,
               t, blockIdx.x * 2 + 1, zs, rmax, rsum, rps, rav, rai);
    grid_barrier(p.bar, &bgen, &bdead);

    // swap h ping-pong
    u16* tp;
    tp = hiH; hiH = hoH; hoH = tp;
    tp = hiM; hiM = hoM; hoM = tp;
    tp = hiL; hiL = hoL; hoL = tp;
  }
}

// Standalone 64x64 bf16x3 GEMM kernel (used once for h0; grid 8*gridN).
__global__ __launch_bounds__(256, 3) void gemm64_kernel(
    const u16* __restrict__ A0h, const u16* __restrict__ A0m, const u16* __restrict__ A0l,
    const u16* __restrict__ A1h, const u16* __restrict__ A1m, const u16* __restrict__ A1l,
    int strideA, int kHalf,
    const u16* __restrict__ Bh, const u16* __restrict__ Bm, const u16* __restrict__ Bl,
    int strideB, int N, int K, int gridN,
    float* __restrict__ C) {
  __shared__ __align__(16) char lds[2][24576];
  int tid = threadIdx.x;
  int w = tid >> 6, l = tid & 63;
  int bid = blockIdx.x;
  int xcd = bid & 7, mIdx = (bid >> 3) & 7, cIdx = bid >> 6;
  int nIdx = xcd * (gridN >> 3) + cIdx;
  int m0 = mIdx * 64, n0 = nIdx * 64;

  int srow = l >> 2;
  int slog = (l & 3) ^ ((l >> 3) & 3);
  size_t aRow = (size_t)(m0 + w * 16 + srow) * strideA + slog * 8;
  size_t bRow = (size_t)(n0 + w * 16 + srow) * strideB + slog * 8;

  int lrow = l & 15, lk8 = l >> 4;
  int xorv = (lrow >> 1) & 3;
  int wr = (w >> 1) * 32, wc = (w & 1) * 32;
  int fOffA = (wr + lrow) * 64 + ((lk8 ^ xorv) << 4);
  int fOffB = (wc + lrow) * 64 + ((lk8 ^ xorv) << 4);

  f32x4 acc[2][2] = {};
  int nch = K >> 5;

#define STAGE64(CH, TB) {                                               \
    int kc = (CH) << 5;                                                 \
    bool hi2 = kc >= kHalf;                                             \
    const u16* Ah2 = hi2 ? A1h : A0h;                                   \
    const u16* Am2 = hi2 ? A1m : A0m;                                   \
    const u16* Al2 = hi2 ? A1l : A0l;                                   \
    size_t ao = aRow + (hi2 ? kc - kHalf : kc);                         \
    size_t bo = bRow + kc;                                              \
    char* Lb = (char*)&lds[TB][0] + w * 1024;                           \
    gld16(Ah2 + ao, Lb + 0 * 4096);                                     \
    gld16(Am2 + ao, Lb + 1 * 4096);                                     \
    gld16(Al2 + ao, Lb + 2 * 4096);                                     \
    gld16(Bh + bo, Lb + 3 * 4096);                                      \
    gld16(Bm + bo, Lb + 4 * 4096);                                      \
    gld16(Bl + bo, Lb + 5 * 4096);                                      \
  }

  STAGE64(0, 0)
  for (int ch = 0; ch < nch; ch++) {
    __syncthreads();
    if (ch + 1 < nch) STAGE64(ch + 1, (ch + 1) & 1)
    const char* base = (const char*)&lds[ch & 1][0];
    bhalf8 af[3][2], bfr[3][2];
#pragma unroll
    for (int p = 0; p < 3; p++) {
#pragma unroll
      for (int m = 0; m < 2; m++)
        af[p][m] = *(const bhalf8*)(base + p * 4096 + fOffA + m * 1024);
#pragma unroll
      for (int n = 0; n < 2; n++)
        bfr[p][n] = *(const bhalf8*)(base + (3 + p) * 4096 + fOffB + n * 1024);
    }
    const int PA[6] = {2, 0, 1, 1, 0, 0};
    const int PB[6] = {0, 2, 1, 0, 1, 0};
#pragma unroll
    for (int pp = 0; pp < 6; pp++) {
#pragma unroll
      for (int m = 0; m < 2; m++) {
#pragma unroll
        for (int n = 0; n < 2; n++) {
          acc[m][n] = __builtin_amdgcn_mfma_f32_16x16x32_bf16(
              af[PA[pp]][m], bfr[PB[pp]][n], acc[m][n], 0, 0, 0);
        }
      }
    }
  }
#undef STAGE64

#pragma unroll
  for (int m = 0; m < 2; m++) {
#pragma unroll
    for (int n = 0; n < 2; n++) {
#pragma unroll
      for (int j = 0; j < 4; j++) {
        int row = m0 + wr + m * 16 + lk8 * 4 + j;
        int col = n0 + wc + n * 16 + lrow;
        C[(size_t)row * N + col] = acc[m][n][j];
      }
    }
  }
}

// Sum nsplit partials + bias -> h planes (used once for h0).
__global__ __launch_bounds__(256) void reduce_bias_planes_kernel(
    const float* __restrict__ P, int pstride, int nsplit,
    const float* __restrict__ bias,
    u16* __restrict__ oh, u16* __restrict__ om, u16* __restrict__ ol) {
  int idx = blockIdx.x * 256 + threadIdx.x;
  if (idx >= B_ * H_ / 4) return;
  size_t off = (size_t)idx * 4;
  float4 s = *(const float4*)&P[off];
  for (int sgl = 1; sgl < nsplit; sgl++) {
    float4 p = *(const float4*)&P[(size_t)sgl * pstride + off];
    s.x += p.x; s.y += p.y; s.z += p.z; s.w += p.w;
  }
  int col = (int)(off & (H_ - 1));
  float4 bv = *(const float4*)&bias[col];
  s.x += bv.x; s.y += bv.y; s.z += bv.z; s.w += bv.w;
  ushort4 vh, vm, vl;
  u16 a, b2, d;
  split3(s.x, a, b2, d); vh.x = a; vm.x = b2; vl.x = d;
  split3(s.y, a, b2, d); vh.y = a; vm.y = b2; vl.y = d;
  split3(s.z, a, b2, d); vh.z = a; vm.z = b2; vl.z = d;
  split3(s.w, a, b2, d); vh.w = a; vm.w = b2; vl.w = d;
  *(ushort4*)&oh[off] = vh;
  *(ushort4*)&om[off] = vm;
  *(ushort4*)&ol[off] = vl;
}

extern "C" void kernel_launch(void* const* d_in, const int* in_sizes, int n_in,
                              void* d_out, int out_size, void* d_ws, size_t ws_size,
                              hipStream_t stream) {
  (void)in_sizes; (void)n_in; (void)out_size; (void)ws_size;
  const float* x     = (const float*)d_in[0];
  const float* agw   = (const float*)d_in[1];
  const float* agb   = (const float*)d_in[2];
  const float* sos   = (const float*)d_in[3];
  const float* emb   = (const float*)d_in[4];
  const float* w_ih  = (const float*)d_in[5];
  const float* w_hh  = (const float*)d_in[6];
  const float* b_ih  = (const float*)d_in[7];
  const float* b_hh  = (const float*)d_in[8];
  const float* out_w = (const float*)d_in[9];
  const float* out_b = (const float*)d_in[10];

  char* w = (char*)d_ws;
  uint32_t* sk = (uint32_t*)w;                      // 256 B used
  uint32_t* bar = (uint32_t*)(w + 4096);            // 544 words, 128-B lines
  size_t o = 8192;
  float* c = (float*)(w + o);        o += (size_t)B_ * H_ * 4;          // 1 MB
#define PLANE3(name, elems) \
  u16* name##H = (u16*)(w + o); o += (size_t)(elems) * 2; \
  u16* name##M = (u16*)(w + o); o += (size_t)(elems) * 2; \
  u16* name##L = (u16*)(w + o); o += (size_t)(elems) * 2;
  PLANE3(e,  B_ * E_)          // 1.5 MB  e activations
  PLANE3(hA, B_ * H_)          // 1.5 MB  h ping
  PLANE3(hB, B_ * H_)          // 1.5 MB  h pong
  PLANE3(xp, B_ * IN_)         // 3 MB    x
  PLANE3(aw, H_ * IN_)         // 3 MB    agent_w^T   [512][1024]
  PLANE3(gw, 2048 * IN_)       // 12 MB   [w_ih;w_hh]^T [2048][1024]
  PLANE3(ow, V_ * H_)          // 6 MB    out_w^T     [2048][512]
  PLANE3(eb, V_ * E_)          // 6 MB    embedding   [2048][512]
#undef PLANE3
  float* P = (float*)(w + o);        // gates/logits buffer [512][2048] fp32 (4 MB)

  float* out = (float*)d_out;
  float* o_seq   = out;                                       // [512,33]
  float* o_probs = out + (size_t)B_ * LP1;                    // [512,33,2048]
  float* o_logp  = o_probs + (size_t)B_ * LP1 * V_;           // [512,33]
  float* o_ent   = o_logp + (size_t)B_ * LP1;                 // [512,33]

  const int BIG = 1 << 30;

  init_keys_kernel<<<1, 1, 0, stream>>>(sk, bar);
  init_state_planes_kernel<<<(B_ * H_ + 255) / 256, 256, 0, stream>>>(sos, c, eH, eM, eL);
  eos_fill_kernel<<<B_, 256, 0, stream>>>(o_seq, o_probs, o_logp, o_ent);

  // one-time conversions
  split_kernel<<<(B_ * IN_ + 255) / 256, 256, 0, stream>>>(x, xpH, xpM, xpL, B_ * IN_);
  split_kernel<<<(V_ * E_ + 255) / 256, 256, 0, stream>>>(emb, ebH, ebM, ebL, V_ * E_);
  transpose_split_kernel<<<dim3(512 / 32, 2048 / 32), 256, 0, stream>>>(
      w_ih, 2048, gwH, gwM, gwL, 1024, 0);
  transpose_split_kernel<<<dim3(512 / 32, 2048 / 32), 256, 0, stream>>>(
      w_hh, 2048, gwH, gwM, gwL, 1024, 512);
  transpose_split_kernel<<<dim3(512 / 32, 2048 / 32), 256, 0, stream>>>(
      out_w, 2048, owH, owM, owL, 512, 0);
  transpose_split_kernel<<<dim3(1024 / 32, 512 / 32), 256, 0, stream>>>(
      agw, 512, awH, awM, awL, 1024, 0);

  // h0 = x @ agent_w + agent_b   (M=512,N=512,K=1024; 64 blocks, one-time)
  gemm64_kernel<<<64, 256, 0, stream>>>(
      xpH, xpM, xpL, xpH, xpM, xpL, IN_, BIG,
      awH, awM, awL, IN_, H_, IN_, 8, P);
  reduce_bias_planes_kernel<<<(B_ * H_ / 4 + 255) / 256, 256, 0, stream>>>(
      P, 0, 1, agb, hAH, hAM, hAL);

  // the whole 32-step loop: one persistent dispatch (plain launch + SW barrier)
  PK pk;
  pk.eH = eH; pk.eM = eM; pk.eL = eL;
  pk.hAH = hAH; pk.hAM = hAM; pk.hAL = hAL;
  pk.hBH = hBH; pk.hBM = hBM; pk.hBL = hBL;
  pk.gwH = gwH; pk.gwM = gwM; pk.gwL = gwL;
  pk.owH = owH; pk.owM = owM; pk.owL = owL;
  pk.ebH = ebH; pk.ebM = ebM; pk.ebL = ebL;
  pk.b_ih = b_ih; pk.b_hh = b_hh; pk.out_b = out_b;
  pk.c = c; pk.G = P; pk.sk = sk; pk.bar = bar;
  pk.o_seq = o_seq; pk.o_probs = o_probs; pk.o_logp = o_logp; pk.o_ent = o_ent;
  rnn_persistent_kernel<<<NBLOCKS, 256, 0, stream>>>(pk);
}

// Round 8
// 1600.597 us; speedup vs baseline: 3.8764x; 3.8764x over previous
//
#include <hip/hip_runtime.h>
#include <math.h>
#include <stdint.h>
#include <stddef.h>

// Problem dims (hard-coded per reference)
#define B_ 512
#define H_ 512
#define E_ 512
#define V_ 2048
#define IN_ 1024
#define LSTEPS 32
#define LP1 33

// JAX threefry mode: 1 = partitionable (JAX >= 0.4.36 default), 0 = original
#define TF_PARTITIONABLE 1

typedef unsigned short u16;
typedef __attribute__((ext_vector_type(8))) short bhalf8;   // 8 bf16 = 4 VGPR
typedef __attribute__((ext_vector_type(4))) float f32x4;

__device__ __forceinline__ void tf2x32(uint32_t k0, uint32_t k1,
                                       uint32_t x0, uint32_t x1,
                                       uint32_t& o0, uint32_t& o1) {
  uint32_t ks2 = k0 ^ k1 ^ 0x1BD11BDAu;
  x0 += k0; x1 += k1;
#define TFR(R) { x0 += x1; x1 = (x1 << (R)) | (x1 >> (32 - (R))); x1 ^= x0; }
  TFR(13) TFR(15) TFR(26) TFR(6)
  x0 += k1; x1 += ks2 + 1u;
  TFR(17) TFR(29) TFR(16) TFR(24)
  x0 += ks2; x1 += k0 + 2u;
  TFR(13) TFR(15) TFR(26) TFR(6)
  x0 += k0; x1 += k1 + 3u;
  TFR(17) TFR(29) TFR(16) TFR(24)
  x0 += k1; x1 += ks2 + 4u;
  TFR(13) TFR(15) TFR(26) TFR(6)
  x0 += ks2; x1 += k0 + 5u;
#undef TFR
  o0 = x0; o1 = x1;
}

__global__ void init_keys_kernel(uint32_t* __restrict__ sk) {
  uint32_t k0 = 0u, k1 = 1u;
  for (int t = 0; t < LSTEPS; t++) {
    uint32_t a0, a1, b0, b1;
#if TF_PARTITIONABLE
    tf2x32(k0, k1, 0u, 0u, a0, a1);
    tf2x32(k0, k1, 0u, 1u, b0, b1);
    sk[2 * t] = b0; sk[2 * t + 1] = b1;
    k0 = a0; k1 = a1;
#else
    tf2x32(k0, k1, 0u, 2u, a0, a1);
    tf2x32(k0, k1, 1u, 3u, b0, b1);
    sk[2 * t] = a1; sk[2 * t + 1] = b1;
    k0 = a0; k1 = b0;
#endif
  }
}

// ---- bf16x3 split (RNE at each stage; hi+mid+lo represents fp32 to 2^-27)
__device__ __forceinline__ void split3(float v, u16& h, u16& m, u16& l) {
  uint32_t u = __float_as_uint(v);
  uint32_t r = (u + 0x7FFFu + ((u >> 16) & 1u)) >> 16;
  h = (u16)r;
  float res = v - __uint_as_float(r << 16);
  uint32_t u2 = __float_as_uint(res);
  uint32_t r2 = (u2 + 0x7FFFu + ((u2 >> 16) & 1u)) >> 16;
  m = (u16)r2;
  float res2 = res - __uint_as_float(r2 << 16);
  uint32_t u3 = __float_as_uint(res2);
  uint32_t r3 = (u3 + 0x7FFFu + ((u3 >> 16) & 1u)) >> 16;
  l = (u16)r3;
}

__global__ __launch_bounds__(256) void init_state_planes_kernel(
    const float* __restrict__ sos, float* __restrict__ c,
    u16* __restrict__ eh, u16* __restrict__ em, u16* __restrict__ el) {
  int idx = blockIdx.x * 256 + threadIdx.x;
  if (idx < B_ * H_) {
    c[idx] = 0.0f;
    u16 a, b2, d;
    split3(sos[idx & (E_ - 1)], a, b2, d);
    eh[idx] = a; em[idx] = b2; el[idx] = d;
  }
}

__global__ __launch_bounds__(256) void eos_fill_kernel(
    float* __restrict__ o_seq, float* __restrict__ o_probs,
    float* __restrict__ o_logp, float* __restrict__ o_ent) {
  int b = blockIdx.x, tid = threadIdx.x;
  float* pr = o_probs + ((size_t)b * LP1 + LSTEPS) * V_;
  for (int v = tid; v < V_; v += 256) pr[v] = 1.0f;
  if (tid == 0) {
    o_seq[b * LP1 + LSTEPS] = 0.0f;
    o_logp[b * LP1 + LSTEPS] = 0.0f;
    o_ent[b * LP1 + LSTEPS] = 0.0f;
  }
}

// elementwise fp32 -> 3 bf16 planes (same layout)
__global__ __launch_bounds__(256) void split_kernel(
    const float* __restrict__ src,
    u16* __restrict__ dh, u16* __restrict__ dm, u16* __restrict__ dl, int n) {
  int i = blockIdx.x * 256 + threadIdx.x;
  if (i < n) {
    u16 a, b2, d;
    split3(src[i], a, b2, d);
    dh[i] = a; dm[i] = b2; dl[i] = d;
  }
}

// bsum[n'] = b_ih + b_hh in gate-interleaved layout n' = h*4 + gate
__global__ __launch_bounds__(256) void bias_pack_kernel(
    const float* __restrict__ b_ih, const float* __restrict__ b_hh,
    float* __restrict__ bsum) {
  int n = blockIdx.x * 256 + threadIdx.x;       // 0..2047
  int h = n >> 2, g = n & 3;
  bsum[n] = b_ih[g * 512 + h] + b_hh[g * 512 + h];
}

// src [srcK][srcN] fp32 -> dst planes [row(n)][dstK] bf16 at column offset kOff.
// gateRemap: out row = (n&511)*4 + (n>>9)   (gate-interleaved for cell fusion)
__global__ __launch_bounds__(256) void transpose_split_kernel(
    const float* __restrict__ src, int srcN,
    u16* __restrict__ dh, u16* __restrict__ dm, u16* __restrict__ dl,
    int dstK, int kOff, int gateRemap) {
  __shared__ float t[32][33];
  int tx = threadIdx.x & 31, ty = threadIdx.x >> 5;   // 32 x 8
  int kt = blockIdx.x * 32, nt = blockIdx.y * 32;
#pragma unroll
  for (int j = 0; j < 4; j++)
    t[ty + j * 8][tx] = src[(size_t)(kt + ty + j * 8) * srcN + nt + tx];
  __syncthreads();
#pragma unroll
  for (int j = 0; j < 4; j++) {
    int n = nt + ty + j * 8;
    int k = kt + tx;
    int nrow = gateRemap ? (((n & 511) << 2) | (n >> 9)) : n;
    u16 a, b2, d;
    split3(t[tx][ty + j * 8], a, b2, d);
    size_t o = (size_t)nrow * dstK + kOff + k;
    dh[o] = a; dm[o] = b2; dl[o] = d;
  }
}

// ---- async global->LDS staging helper (16B per lane, wave-uniform LDS base)
typedef __attribute__((address_space(1))) const void GASV;
typedef __attribute__((address_space(3))) void LASV;
__device__ __forceinline__ void gld16(const void* g, void* l) {
  __builtin_amdgcn_global_load_lds((GASV*)g, (LASV*)l, 16, 0, 0);
}

__device__ __forceinline__ float sigm(float x) { return 1.0f / (1.0f + expf(-x)); }

// ============================================================================
// Shared GEMM decode/K-loop macros (verified R2/R3 swizzle + MFMA layout).
// 256 threads, 4 waves, 64x64 tile, wave-tile 32x32, acc 2x2 of 16x16x32_bf16.
// LDS: 2 bufs x 6 planes x [64 rows][32 k] bf16 = 48 KB.
// ============================================================================
#define GEMM_DECODE(N_)                                                     \
  int tid = threadIdx.x;                                                    \
  int w = tid >> 6, l = tid & 63;                                           \
  int bid = blockIdx.x;                                                     \
  int gridN = (N_) >> 6;                                                    \
  int xcd = bid & 7, mIdx = (bid >> 3) & 7, cIdx = bid >> 6;                \
  int nIdx = xcd * (gridN >> 3) + cIdx;                                     \
  int m0 = mIdx * 64, n0 = nIdx * 64;                                       \
  int srow = l >> 2;                                                        \
  int slog = (l & 3) ^ ((l >> 3) & 3);                                      \
  int lrow = l & 15, lk8 = l >> 4;                                          \
  int xorv = (lrow >> 1) & 3;                                               \
  int wr = (w >> 1) * 32, wc = (w & 1) * 32;                                \
  int fOffA = (wr + lrow) * 64 + ((lk8 ^ xorv) << 4);                       \
  int fOffB = (wc + lrow) * 64 + ((lk8 ^ xorv) << 4);

#define STAGE6(CH, TB, LDSB)  {                                             \
    int kc = (CH) << 5;                                                     \
    bool hi2 = kc >= kHalf;                                                 \
    const u16* Ah2 = hi2 ? A1h : A0h;                                       \
    const u16* Am2 = hi2 ? A1m : A0m;                                       \
    const u16* Al2 = hi2 ? A1l : A0l;                                       \
    size_t ao = aRow + (hi2 ? kc - kHalf : kc);                             \
    size_t bo = bRow + kc;                                                  \
    char* Lb = (LDSB) + (TB) * 24576 + w * 1024;                            \
    gld16(Ah2 + ao, Lb + 0 * 4096);                                         \
    gld16(Am2 + ao, Lb + 1 * 4096);                                         \
    gld16(Al2 + ao, Lb + 2 * 4096);                                         \
    gld16(Bh + bo, Lb + 3 * 4096);                                          \
    gld16(Bm + bo, Lb + 4 * 4096);                                          \
    gld16(Bl + bo, Lb + 5 * 4096);                                          \
  }

#define GEMM_KLOOP(LDSB)                                                    \
  STAGE6(0, 0, LDSB)                                                        \
  for (int ch = 0; ch < nch; ch++) {                                        \
    __syncthreads();                                                        \
    if (ch + 1 < nch) STAGE6(ch + 1, (ch + 1) & 1, LDSB)                    \
    const char* base = (LDSB) + (ch & 1) * 24576;                           \
    bhalf8 af[3][2], bfr[3][2];                                             \
    _Pragma("unroll")                                                       \
    for (int p = 0; p < 3; p++) {                                           \
      _Pragma("unroll")                                                     \
      for (int m = 0; m < 2; m++)                                           \
        af[p][m] = *(const bhalf8*)(base + p * 4096 + fOffA + m * 1024);    \
      _Pragma("unroll")                                                     \
      for (int n = 0; n < 2; n++)                                           \
        bfr[p][n] = *(const bhalf8*)(base + (3 + p) * 4096 + fOffB + n * 1024); \
    }                                                                       \
    const int PA[6] = {2, 0, 1, 1, 0, 0};                                   \
    const int PB[6] = {0, 2, 1, 0, 1, 0};                                   \
    _Pragma("unroll")                                                       \
    for (int pp = 0; pp < 6; pp++) {                                        \
      _Pragma("unroll")                                                     \
      for (int m = 0; m < 2; m++) {                                         \
        _Pragma("unroll")                                                   \
        for (int n = 0; n < 2; n++) {                                       \
          acc[m][n] = __builtin_amdgcn_mfma_f32_16x16x32_bf16(              \
              af[PA[pp]][m], bfr[PB[pp]][n], acc[m][n], 0, 0, 0);           \
        }                                                                   \
      }                                                                     \
    }                                                                       \
  }

// Standalone bf16x3 GEMM -> fp32 C (h0 + logits). grid = 8 * (N/64).
__global__ __launch_bounds__(256, 3) void gemm64_kernel(
    const u16* __restrict__ A0h, const u16* __restrict__ A0m, const u16* __restrict__ A0l,
    const u16* __restrict__ A1h, const u16* __restrict__ A1m, const u16* __restrict__ A1l,
    int strideA, int kHalf,
    const u16* __restrict__ Bh, const u16* __restrict__ Bm, const u16* __restrict__ Bl,
    int strideB, int N, int K,
    float* __restrict__ C) {
  __shared__ __align__(16) char lds[2][24576];
  GEMM_DECODE(N)
  size_t aRow = (size_t)(m0 + w * 16 + srow) * strideA + slog * 8;
  size_t bRow = (size_t)(n0 + w * 16 + srow) * strideB + slog * 8;
  f32x4 acc[2][2] = {};
  int nch = K >> 5;
  GEMM_KLOOP((char*)&lds[0][0])
  // C/D layout: col = lane&15, row = (lane>>4)*4 + reg  [m89-verified]
#pragma unroll
  for (int m = 0; m < 2; m++) {
#pragma unroll
    for (int n = 0; n < 2; n++) {
#pragma unroll
      for (int j = 0; j < 4; j++) {
        int row = m0 + wr + m * 16 + lk8 * 4 + j;
        int col = n0 + wc + n * 16 + lrow;
        C[(size_t)row * N + col] = acc[m][n][j];
      }
    }
  }
}

// Fused gates GEMM + LSTM cell. B = gw' (gate-interleaved n' = h*4+gate,
// [2048][1024]); A = e planes (k<512) / h planes (k>=512).
// Epilogue: acc tile -> LDS -> per-(b,h) float4 = [i,f,g,o] -> cell ->
// c fp32 + h bf16x3 planes. Bit-identical cell math to R3's cell kernel.
__global__ __launch_bounds__(256, 3) void gemm_gates_cell_kernel(
    const u16* __restrict__ A0h, const u16* __restrict__ A0m, const u16* __restrict__ A0l,
    const u16* __restrict__ A1h, const u16* __restrict__ A1m, const u16* __restrict__ A1l,
    const u16* __restrict__ Bh, const u16* __restrict__ Bm, const u16* __restrict__ Bl,
    const float* __restrict__ bsum,
    float* __restrict__ c,
    u16* __restrict__ hoH, u16* __restrict__ hoM, u16* __restrict__ hoL) {
  __shared__ __align__(16) char lds[2][24576];
  const int strideA = E_, strideB = IN_, kHalf = E_;
  GEMM_DECODE(2048)
  size_t aRow = (size_t)(m0 + w * 16 + srow) * strideA + slog * 8;
  size_t bRow = (size_t)(n0 + w * 16 + srow) * strideB + slog * 8;
  f32x4 acc[2][2] = {};
  int nch = IN_ >> 5;                              // 32 chunks
  GEMM_KLOOP((char*)&lds[0][0])

  // ---- fused cell epilogue ----
  __syncthreads();                                 // all frag reads done
  float* tile = (float*)&lds[0][0];                // [64][68] fp32 = 17.4 KB
#pragma unroll
  for (int m = 0; m < 2; m++) {
#pragma unroll
    for (int n = 0; n < 2; n++) {
#pragma unroll
      for (int j = 0; j < 4; j++) {
        int r = wr + m * 16 + lk8 * 4 + j;
        int cc = wc + n * 16 + lrow;
        tile[r * 68 + cc] = acc[m][n][j];
      }
    }
  }
  __syncthreads();
  int hbase = n0 >> 2;                             // 16 h values per block
#pragma unroll
  for (int p = 0; p < 4; p++) {
    int id = tid + p * 256;                        // 0..1023
    int bl = id >> 4, hl = id & 15;
    float4 g = *(float4*)&tile[bl * 68 + hl * 4];  // [i,f,g,o]
    float4 bs = *(const float4*)&bsum[n0 + hl * 4];
    float ig = g.x + bs.x, fg = g.y + bs.y, gg = g.z + bs.z, og = g.w + bs.w;
    size_t ci = (size_t)(m0 + bl) * 512 + hbase + hl;
    float cold = c[ci];
    float cv = sigm(fg) * cold + sigm(ig) * tanhf(gg);
    float hv = sigm(og) * tanhf(cv);
    c[ci] = cv;
    u16 a, b2, d;
    split3(hv, a, b2, d);
    hoH[ci] = a; hoM[ci] = b2; hoL[ci] = d;
  }
}

// Sum nsplit partials + bias -> h planes (used once for h0).
__global__ __launch_bounds__(256) void reduce_bias_planes_kernel(
    const float* __restrict__ P, int pstride, int nsplit,
    const float* __restrict__ bias,
    u16* __restrict__ oh, u16* __restrict__ om, u16* __restrict__ ol) {
  int idx = blockIdx.x * 256 + threadIdx.x;
  if (idx >= B_ * H_ / 4) return;
  size_t off = (size_t)idx * 4;
  float4 s = *(const float4*)&P[off];
  for (int sgl = 1; sgl < nsplit; sgl++) {
    float4 p = *(const float4*)&P[(size_t)sgl * pstride + off];
    s.x += p.x; s.y += p.y; s.z += p.z; s.w += p.w;
  }
  int col = (int)(off & (H_ - 1));
  float4 bv = *(const float4*)&bias[col];
  s.x += bv.x; s.y += bv.y; s.z += bv.z; s.w += bv.w;
  ushort4 vh, vm, vl;
  u16 a, b2, d;
  split3(s.x, a, b2, d); vh.x = a; vm.x = b2; vl.x = d;
  split3(s.y, a, b2, d); vh.y = a; vm.y = b2; vl.y = d;
  split3(s.z, a, b2, d); vh.z = a; vm.z = b2; vl.z = d;
  split3(s.w, a, b2, d); vh.w = a; vm.w = b2; vl.w = d;
  *(ushort4*)&oh[off] = vh;
  *(ushort4*)&om[off] = vm;
  *(ushort4*)&ol[off] = vl;
}

// Per-row: logits (+out_b), log_softmax, entropy, probs write,
// threefry gumbel argmax sample, logp gather, embedding-plane gather.
__global__ __launch_bounds__(256) void sample_step_kernel(
    const float* __restrict__ Z, const float* __restrict__ out_b,
    const uint32_t* __restrict__ skv,
    const u16* __restrict__ ebH, const u16* __restrict__ ebM, const u16* __restrict__ ebL,
    u16* __restrict__ eh, u16* __restrict__ em_, u16* __restrict__ el_,
    float* __restrict__ o_seq, float* __restrict__ o_probs,
    float* __restrict__ o_logp, float* __restrict__ o_ent, int t) {
  __shared__ float zs[V_];
  __shared__ float rmax[4], rsum[4], rps[4], rav[4];
  __shared__ int rai[4];
  int tid = threadIdx.x, b = blockIdx.x;
  int wid = tid >> 6;
  const float* pr0 = Z + (size_t)b * V_ + tid * 8;
  float4 za = *(const float4*)pr0;
  float4 zb = *(const float4*)(pr0 + 4);
  {
    float4 oa = *(const float4*)(out_b + tid * 8);
    float4 ob = *(const float4*)(out_b + tid * 8 + 4);
    za.x += oa.x; za.y += oa.y; za.z += oa.z; za.w += oa.w;
    zb.x += ob.x; zb.y += ob.y; zb.z += ob.z; zb.w += ob.w;
  }
  float zv[8] = {za.x, za.y, za.z, za.w, zb.x, zb.y, zb.z, zb.w};
  *(float4*)&zs[tid * 8] = za;
  *(float4*)&zs[tid * 8 + 4] = zb;

  float m = zv[0];
#pragma unroll
  for (int i = 1; i < 8; i++) m = fmaxf(m, zv[i]);
  for (int off = 32; off; off >>= 1) m = fmaxf(m, __shfl_xor(m, off));
  if ((tid & 63) == 0) rmax[wid] = m;
  __syncthreads();
  m = fmaxf(fmaxf(rmax[0], rmax[1]), fmaxf(rmax[2], rmax[3]));

  float sh[8];
  float ssum = 0.f;
#pragma unroll
  for (int i = 0; i < 8; i++) { sh[i] = zv[i] - m; ssum += expf(sh[i]); }
  for (int off = 32; off; off >>= 1) ssum += __shfl_xor(ssum, off);
  if ((tid & 63) == 0) rsum[wid] = ssum;
  __syncthreads();
  float S = (rsum[0] + rsum[1]) + (rsum[2] + rsum[3]);
  float ls = logf(S);

  uint32_t sk0 = skv[2 * t], sk1 = skv[2 * t + 1];
  float psum = 0.f;
  float best = -INFINITY;
  int bi = 0;
  float pv[8];
#pragma unroll
  for (int i = 0; i < 8; i++) {
    float s = sh[i] - ls;
    float p = expf(s);
    pv[i] = p;
    psum += p * s;
    int v = tid * 8 + i;
    uint32_t o0, o1, bits;
#if TF_PARTITIONABLE
    uint32_t j = (uint32_t)(b * V_ + v);
    tf2x32(sk0, sk1, 0u, j, o0, o1);
    bits = o0 ^ o1;
#else
    uint32_t j = (uint32_t)(b * V_ + v);
    const uint32_t n2 = (uint32_t)(B_ * V_ / 2);
    if (j < n2) { tf2x32(sk0, sk1, j, j + n2, o0, o1); bits = o0; }
    else       { tf2x32(sk0, sk1, j - n2, j, o0, o1); bits = o1; }
#endif
    float f = __uint_as_float((bits >> 9) | 0x3f800000u) - 1.0f;
    float u = fmaxf(f, 1.17549435e-38f);
    float g = -logf(-logf(u));
    float a = s + g;
    if (a > best) { best = a; bi = v; }
  }
  float* prw = o_probs + ((size_t)b * LP1 + t) * V_ + tid * 8;
  *(float4*)prw = make_float4(pv[0], pv[1], pv[2], pv[3]);
  *(float4*)(prw + 4) = make_float4(pv[4], pv[5], pv[6], pv[7]);

  for (int off = 32; off; off >>= 1) psum += __shfl_xor(psum, off);
  for (int off = 32; off; off >>= 1) {
    float ov = __shfl_xor(best, off);
    int oi = __shfl_xor(bi, off);
    if (ov > best || (ov == best && oi < bi)) { best = ov; bi = oi; }
  }
  if ((tid & 63) == 0) { rps[wid] = psum; rav[wid] = best; rai[wid] = bi; }
  __syncthreads();
  float ent = -((rps[0] + rps[1]) + (rps[2] + rps[3]));
  float bv2 = rav[0]; int sym = rai[0];
#pragma unroll
  for (int w2 = 1; w2 < 4; w2++) {
    if (rav[w2] > bv2 || (rav[w2] == bv2 && rai[w2] < sym)) { bv2 = rav[w2]; sym = rai[w2]; }
  }
  const u16* gh = ebH + (size_t)sym * E_;
  const u16* gm = ebM + (size_t)sym * E_;
  const u16* gl = ebL + (size_t)sym * E_;
  for (int k2 = tid; k2 < E_; k2 += 256) {
    eh[(size_t)b * E_ + k2]  = gh[k2];
    em_[(size_t)b * E_ + k2] = gm[k2];
    el_[(size_t)b * E_ + k2] = gl[k2];
  }
  if (tid == 0) {
    float s_sym = (zs[sym] - m) - ls;
    o_seq[b * LP1 + t] = (float)sym;
    o_logp[b * LP1 + t] = s_sym;
    o_ent[b * LP1 + t] = ent;
  }
}

extern "C" void kernel_launch(void* const* d_in, const int* in_sizes, int n_in,
                              void* d_out, int out_size, void* d_ws, size_t ws_size,
                              hipStream_t stream) {
  (void)in_sizes; (void)n_in; (void)out_size; (void)ws_size;
  const float* x     = (const float*)d_in[0];
  const float* agw   = (const float*)d_in[1];
  const float* agb   = (const float*)d_in[2];
  const float* sos   = (const float*)d_in[3];
  const float* emb   = (const float*)d_in[4];
  const float* w_ih  = (const float*)d_in[5];
  const float* w_hh  = (const float*)d_in[6];
  const float* b_ih  = (const float*)d_in[7];
  const float* b_hh  = (const float*)d_in[8];
  const float* out_w = (const float*)d_in[9];
  const float* out_b = (const float*)d_in[10];

  char* w = (char*)d_ws;
  uint32_t* sk = (uint32_t*)w;                      // 256 B used
  float* bsum = (float*)(w + 4096);                 // 8 KB  gate-interleaved bias
  size_t o = 4096 + 8192;
  float* c = (float*)(w + o);        o += (size_t)B_ * H_ * 4;          // 1 MB
#define PLANE3(name, elems) \
  u16* name##H = (u16*)(w + o); o += (size_t)(elems) * 2; \
  u16* name##M = (u16*)(w + o); o += (size_t)(elems) * 2; \
  u16* name##L = (u16*)(w + o); o += (size_t)(elems) * 2;
  PLANE3(e,  B_ * E_)          // 1.5 MB  e activations
  PLANE3(hA, B_ * H_)          // 1.5 MB  h ping
  PLANE3(hB, B_ * H_)          // 1.5 MB  h pong
  PLANE3(xp, B_ * IN_)         // 3 MB    x
  PLANE3(aw, H_ * IN_)         // 3 MB    agent_w^T   [512][1024]
  PLANE3(gw, 2048 * IN_)       // 12 MB   [w_ih;w_hh]^T gate-interleaved [2048][1024]
  PLANE3(ow, V_ * H_)          // 6 MB    out_w^T     [2048][512]
  PLANE3(eb, V_ * E_)          // 6 MB    embedding   [2048][512]
#undef PLANE3
  float* P = (float*)(w + o);        // logits buffer [512][2048] fp32 (4 MB)

  float* out = (float*)d_out;
  float* o_seq   = out;                                       // [512,33]
  float* o_probs = out + (size_t)B_ * LP1;                    // [512,33,2048]
  float* o_logp  = o_probs + (size_t)B_ * LP1 * V_;           // [512,33]
  float* o_ent   = o_logp + (size_t)B_ * LP1;                 // [512,33]

  const int BIG = 1 << 30;

  init_keys_kernel<<<1, 1, 0, stream>>>(sk);
  init_state_planes_kernel<<<(B_ * H_ + 255) / 256, 256, 0, stream>>>(sos, c, eH, eM, eL);
  eos_fill_kernel<<<B_, 256, 0, stream>>>(o_seq, o_probs, o_logp, o_ent);
  bias_pack_kernel<<<8, 256, 0, stream>>>(b_ih, b_hh, bsum);

  // one-time conversions
  split_kernel<<<(B_ * IN_ + 255) / 256, 256, 0, stream>>>(x, xpH, xpM, xpL, B_ * IN_);
  split_kernel<<<(V_ * E_ + 255) / 256, 256, 0, stream>>>(emb, ebH, ebM, ebL, V_ * E_);
  transpose_split_kernel<<<dim3(512 / 32, 2048 / 32), 256, 0, stream>>>(
      w_ih, 2048, gwH, gwM, gwL, 1024, 0, 1);
  transpose_split_kernel<<<dim3(512 / 32, 2048 / 32), 256, 0, stream>>>(
      w_hh, 2048, gwH, gwM, gwL, 1024, 512, 1);
  transpose_split_kernel<<<dim3(512 / 32, 2048 / 32), 256, 0, stream>>>(
      out_w, 2048, owH, owM, owL, 512, 0, 0);
  transpose_split_kernel<<<dim3(1024 / 32, 512 / 32), 256, 0, stream>>>(
      agw, 512, awH, awM, awL, 1024, 0, 0);

  // h0 = x @ agent_w + agent_b   (M=512,N=512,K=1024; 64 blocks, one-time)
  gemm64_kernel<<<64, 256, 0, stream>>>(
      xpH, xpM, xpL, xpH, xpM, xpL, IN_, BIG,
      awH, awM, awL, IN_, H_, IN_, P);
  reduce_bias_planes_kernel<<<(B_ * H_ / 4 + 255) / 256, 256, 0, stream>>>(
      P, 0, 1, agb, hAH, hAM, hAL);

  for (int t = 0; t < LSTEPS; t++) {
    u16 *hiH = (t & 1) ? hBH : hAH, *hiM = (t & 1) ? hBM : hAM, *hiL = (t & 1) ? hBL : hAL;
    u16 *hoH = (t & 1) ? hAH : hBH, *hoM = (t & 1) ? hAM : hBM, *hoL = (t & 1) ? hAL : hBL;
    // fused: gates = [e|h] @ gw' -> cell -> c, h planes   (grid 8x32)
    gemm_gates_cell_kernel<<<256, 256, 0, stream>>>(
        eH, eM, eL, hiH, hiM, hiL,
        gwH, gwM, gwL, bsum, c, hoH, hoM, hoL);
    // logits = h @ out_w  (K=512, grid 8x32)
    gemm64_kernel<<<256, 256, 0, stream>>>(
        hoH, hoM, hoL, hoH, hoM, hoL, H_, BIG,
        owH, owM, owL, H_, 2048, H_, P);
    sample_step_kernel<<<B_, 256, 0, stream>>>(
        P, out_b, sk, ebH, ebM, ebL, eH, eM, eL,
        o_seq, o_probs, o_logp, o_ent, t);
  }
}